// Round 8
// baseline (62.348 us; speedup 1.0000x reference)
//
#include <hip/hip_runtime.h>
#include <stdint.h>

// Problem constants
#define N_ANCHOR 2048
#define DIM 128
#define NEG_PER 15
#define NZ 32768                    // 2048*16 candidate rows
#define NROWS (N_ANCHOR + NZ)       // 34816
#define INV_TEMP 3.3333333333333335f
#define LOG2E 1.4426950408889634f
#define LN2 0.6931471805599453f
#define TOTAL_ELEMS 67108864.0f
#define A_PRESCALE (INV_TEMP * LOG2E)   // folded into anchor normalization

#define BM 256                      // rows per block (4 waves x 64)
#define CPB 256                     // cols per block (8 tiles of 32)
#define NT 8
#define RB (N_ANCHOR / BM)          // 8
#define CG (NZ / CPB)               // 128
#define NBLK (RB * CG)              // 1024

using bf16x8 = __attribute__((ext_vector_type(8))) __bf16;
using f32x16 = __attribute__((ext_vector_type(16))) float;

// ---------- helpers ----------
static __device__ __forceinline__ unsigned short f2bf(float f) {
  union { float f; unsigned u; } v; v.f = f;
  unsigned r = v.u + 0x7FFF + ((v.u >> 16) & 1);   // round-to-nearest-even
  return (unsigned short)(r >> 16);
}

// ---------- kernel 1: L2-normalize rows, cast to bf16 ----------
// Anchors -> row-major a_bf (prescaled by INV_TEMP*LOG2E).
// z rows  -> FRAGMENT-MAJOR z_bf: for col c, dim d:
//   off = (c>>5)*4096 + (d>>4)*512 + ((c&31) + 32*((d>>3)&1))*8 + (d&7)
// so a gemm B-frag load is base + lane*8 shorts (fully coalesced).
__global__ __launch_bounds__(256) void norm_kernel(
    const float* __restrict__ anchor, const float* __restrict__ pos,
    const float* __restrict__ neg, unsigned short* __restrict__ a_bf,
    unsigned short* __restrict__ z_bf) {
  int row = blockIdx.x * 8 + (threadIdx.x >> 5);
  int l32 = threadIdx.x & 31;
  const float* src;
  float pre;
  bool is_a = row < N_ANCHOR;
  int c = row - N_ANCHOR;     // z col index if !is_a
  if (is_a) {
    src = anchor + row * DIM;
    pre = A_PRESCALE;
  } else {
    int j = c >> 4, k = c & 15;
    src = (k == 0) ? (pos + j * DIM) : (neg + (j * NEG_PER + (k - 1)) * DIM);
    pre = 1.0f;
  }
  float4 v = ((const float4*)src)[l32];
  float s = v.x * v.x + v.y * v.y + v.z * v.z + v.w * v.w;
  #pragma unroll
  for (int o = 16; o >= 1; o >>= 1) s += __shfl_xor(s, o, 32);
  float scale = pre / fmaxf(sqrtf(s), 1e-12f);
  ushort4 o4;
  o4.x = f2bf(v.x * scale); o4.y = f2bf(v.y * scale);
  o4.z = f2bf(v.z * scale); o4.w = f2bf(v.w * scale);
  if (is_a) {
    ((ushort4*)(a_bf + row * DIM))[l32] = o4;
  } else {
    size_t off = (size_t)(c >> 5) * 4096 + (l32 >> 2) * 512 +
                 ((c & 31) + 32 * ((l32 >> 1) & 1)) * 8 + (l32 & 1) * 4;
    *(ushort4*)(z_bf + off) = o4;
  }
}

// ---------- kernel 2: closed-form diagonal from RAW f32 inputs ----------
// dpart[i] = A_PRESCALE * <a_i/||a_i||, sum_k z_ik/||z_ik||>   (t-units)
__global__ __launch_bounds__(256) void diag_kernel(
    const float* __restrict__ anchor, const float* __restrict__ pos,
    const float* __restrict__ neg, float* __restrict__ dpart) {
  int i    = blockIdx.x * 4 + (threadIdx.x >> 6);
  int lane = threadIdx.x & 63;
  float2 a2 = ((const float2*)(anchor + i * DIM))[lane];
  float na = a2.x * a2.x + a2.y * a2.y;
  #pragma unroll
  for (int o = 32; o >= 1; o >>= 1) na += __shfl_xor(na, o);
  float sa = A_PRESCALE / fmaxf(sqrtf(na), 1e-12f);
  float s0 = 0.f, s1 = 0.f;
  #pragma unroll 1
  for (int k = 0; k < 16; ++k) {
    const float* zr = (k == 0) ? (pos + i * DIM)
                               : (neg + (i * NEG_PER + (k - 1)) * DIM);
    float2 z2 = ((const float2*)zr)[lane];
    float nz = z2.x * z2.x + z2.y * z2.y;
    #pragma unroll
    for (int o = 32; o >= 1; o >>= 1) nz += __shfl_xor(nz, o);
    float sz = 1.0f / fmaxf(sqrtf(nz), 1e-12f);
    s0 += z2.x * sz;
    s1 += z2.y * sz;
  }
  float d = (a2.x * sa) * s0 + (a2.y * sa) * s1;
  #pragma unroll
  for (int o = 32; o >= 1; o >>= 1) d += __shfl_xor(d, o);
  if (lane == 0) dpart[i] = d;
}

// ---------- kernel 3: fused GEMM + loss — NO LDS, NO BARRIERS ----------
// R7 post-mortem: per-phase cost ~3000cyc regardless of waves or work ->
// the stage/vmcnt/barrier lockstep itself is the limiter. Here every wave is
// an independent stream: A frags in regs (once), B frags loaded per 32-col
// tile directly from fragment-major global (coalesced, L1/L2-hot).
// Epilogue is position-independent (diag handled separately).
__global__ __launch_bounds__(256) void gemm_loss_kernel(
    const unsigned short* __restrict__ a_bf,
    const unsigned short* __restrict__ z_bf,
    float* __restrict__ partial) {
  __shared__ float red[4];

  const int t    = threadIdx.x;
  const int bid  = blockIdx.x;
  // bijective XCD swizzle (1024 % 8 == 0): each XCD works one 16-cgi slice
  // (1MB of B, L2-resident) across all 8 row-blocks.
  const int lg   = ((bid & 7) << 7) | (bid >> 3);
  const int rb   = lg & 7;
  const int cgi  = lg >> 3;
  const int wave = t >> 6;
  const int lane = t & 63;

  // A fragments: af[i2][ks] = a[rb*256 + wave*64 + i2*32 + (lane&31)]
  //                            [ks*16 + (lane>>5)*8 .. +8]
  bf16x8 af[2][8];
  {
    const unsigned short* Ar =
        a_bf + (size_t)(rb * BM + wave * 64 + (lane & 31)) * DIM +
        (lane >> 5) * 8;
    #pragma unroll
    for (int i = 0; i < 2; ++i)
      #pragma unroll
      for (int ks = 0; ks < 8; ++ks)
        af[i][ks] = *(const bf16x8*)(Ar + i * 32 * DIM + ks * 16);
  }

  float relsum = 0.f, logacc = 0.f;

  #pragma unroll 1
  for (int tt = 0; tt < NT; ++tt) {
    // B fragments for this 32-col tile: coalesced, base + lane*16B
    const unsigned short* Bt =
        z_bf + (size_t)(cgi * NT + tt) * 4096 + lane * 8;
    bf16x8 b[8];
    #pragma unroll
    for (int ks = 0; ks < 8; ++ks)
      b[ks] = *(const bf16x8*)(Bt + ks * 512);

    f32x16 acc0, acc1;
    acc0 = 0.0f; acc1 = 0.0f;
    #pragma unroll
    for (int ks = 0; ks < 8; ++ks) {
      acc0 = __builtin_amdgcn_mfma_f32_32x32x16_bf16(af[0][ks], b[ks], acc0, 0, 0, 0);
      acc1 = __builtin_amdgcn_mfma_f32_32x32x16_bf16(af[1][ks], b[ks], acc1, 0, 0, 0);
    }

    // epilogue per element: relu-add + (exp2 + fma) product trick
    float rl[4] = {0.f, 0.f, 0.f, 0.f};
    float pr[4] = {1.f, 1.f, 1.f, 1.f};
    #pragma unroll
    for (int e = 0; e < 16; ++e) {
      float tv = acc0[e];
      int r = e & 3;
      rl[r] += fmaxf(tv, 0.f);
      pr[r] = fmaf(pr[r], __builtin_amdgcn_exp2f(-fabsf(tv)), pr[r]);
    }
    #pragma unroll
    for (int e = 0; e < 16; ++e) {
      float tv = acc1[e];
      int r = e & 3;
      rl[r] += fmaxf(tv, 0.f);
      pr[r] = fmaf(pr[r], __builtin_amdgcn_exp2f(-fabsf(tv)), pr[r]);
    }
    relsum += (rl[0] + rl[1]) + (rl[2] + rl[3]);
    // 8 factors in [1,2] per chain -> product <= 2^32: safe
    logacc += __builtin_amdgcn_logf((pr[0] * pr[1]) * (pr[2] * pr[3]));
  }

  float local = relsum + logacc;
  #pragma unroll
  for (int o = 32; o >= 1; o >>= 1) local += __shfl_xor(local, o);
  if (lane == 0) red[wave] = local;
  __syncthreads();
  if (t == 0) partial[bid] = (red[0] + red[1]) + (red[2] + red[3]);
}

// ---------- kernel 4: final reduction ----------
__global__ __launch_bounds__(256) void reduce_kernel(
    const float* __restrict__ partial, const float* __restrict__ dpart,
    float* __restrict__ out) {
  int t = threadIdx.x;
  float s = 0.0f;
  for (int i = t; i < NBLK; i += 256) s += partial[i];
  for (int i = t; i < N_ANCHOR; i += 256) s -= dpart[i];
  #pragma unroll
  for (int o = 32; o >= 1; o >>= 1) s += __shfl_xor(s, o);
  __shared__ float red[4];
  if ((t & 63) == 0) red[t >> 6] = s;
  __syncthreads();
  if (t == 0)
    out[0] = ((red[0] + red[1]) + (red[2] + red[3])) * (LN2 / TOTAL_ELEMS);
}

extern "C" void kernel_launch(void* const* d_in, const int* in_sizes, int n_in,
                              void* d_out, int out_size, void* d_ws, size_t ws_size,
                              hipStream_t stream) {
  const float* anchor = (const float*)d_in[0];
  const float* pos    = (const float*)d_in[1];
  const float* neg    = (const float*)d_in[2];
  char* ws = (char*)d_ws;
  unsigned short* a_bf = (unsigned short*)ws;                    // 512 KB
  unsigned short* z_bf = (unsigned short*)(ws + 524288);         // 8 MB
  float* partial       = (float*)(ws + 524288 + 8388608);        // 4 KB
  float* dpart         = (float*)(ws + 524288 + 8388608 + 4096); // 8 KB

  norm_kernel<<<dim3(NROWS / 8), dim3(256), 0, stream>>>(
      anchor, pos, neg, a_bf, z_bf);
  diag_kernel<<<dim3(N_ANCHOR / 4), dim3(256), 0, stream>>>(
      anchor, pos, neg, dpart);
  gemm_loss_kernel<<<dim3(NBLK), dim3(256), 0, stream>>>(a_bf, z_bf, partial);
  reduce_kernel<<<dim3(1), dim3(256), 0, stream>>>(partial, dpart,
                                                   (float*)d_out);
}

// Round 9
// 51.053 us; speedup vs baseline: 1.2212x; 1.2212x over previous
//
#include <hip/hip_runtime.h>
#include <stdint.h>

// Problem constants
#define N_ANCHOR 2048
#define DIM 128
#define NEG_PER 15
#define NZ 32768                    // 2048*16 candidate rows
#define NROWS (N_ANCHOR + NZ)       // 34816
#define INV_TEMP 3.3333333333333335f
#define LOG2E 1.4426950408889634f
#define LN2 0.6931471805599453f
#define TOTAL_ELEMS 67108864.0f
#define A_PRESCALE (INV_TEMP * LOG2E)   // folded into anchor normalization

#define BM 256                      // rows per block (4 waves x 64)
#define CPB 256                     // cols per block (8 tiles of 32)
#define NT 8
#define RB (N_ANCHOR / BM)          // 8
#define CG (NZ / CPB)               // 128
#define NBLK (RB * CG)              // 1024

using bf16x8 = __attribute__((ext_vector_type(8))) __bf16;
using f32x16 = __attribute__((ext_vector_type(16))) float;

// ---------- helpers ----------
static __device__ __forceinline__ unsigned short f2bf(float f) {
  union { float f; unsigned u; } v; v.f = f;
  unsigned r = v.u + 0x7FFF + ((v.u >> 16) & 1);   // round-to-nearest-even
  return (unsigned short)(r >> 16);
}

static __device__ __forceinline__ float bf2f(unsigned short u) {
  union { unsigned u; float f; } v; v.u = ((unsigned)u) << 16;
  return v.f;
}

static __device__ __forceinline__ void gload_lds16(const void* g, void* l) {
  __builtin_amdgcn_global_load_lds(
      (const __attribute__((address_space(1))) void*)g,
      (__attribute__((address_space(3))) void*)l, 16, 0, 0);
}

// ---------- kernel 1: L2-normalize rows, cast to bf16 (row-major) ----------
__global__ __launch_bounds__(256) void norm_kernel(
    const float* __restrict__ anchor, const float* __restrict__ pos,
    const float* __restrict__ neg, unsigned short* __restrict__ a_bf,
    unsigned short* __restrict__ z_bf) {
  int row = blockIdx.x * 8 + (threadIdx.x >> 5);
  int l32 = threadIdx.x & 31;
  const float* src;
  unsigned short* dst;
  float pre;
  if (row < N_ANCHOR) {
    src = anchor + row * DIM;
    dst = a_bf + row * DIM;
    pre = A_PRESCALE;
  } else {
    int rz = row - N_ANCHOR;
    int j = rz >> 4, k = rz & 15;
    src = (k == 0) ? (pos + j * DIM) : (neg + (j * NEG_PER + (k - 1)) * DIM);
    dst = z_bf + rz * DIM;
    pre = 1.0f;
  }
  float4 v = ((const float4*)src)[l32];
  float s = v.x * v.x + v.y * v.y + v.z * v.z + v.w * v.w;
  #pragma unroll
  for (int o = 16; o >= 1; o >>= 1) s += __shfl_xor(s, o, 32);
  float scale = pre / fmaxf(sqrtf(s), 1e-12f);
  ushort4 o4;
  o4.x = f2bf(v.x * scale); o4.y = f2bf(v.y * scale);
  o4.z = f2bf(v.z * scale); o4.w = f2bf(v.w * scale);
  ((ushort4*)dst)[l32] = o4;
}

// ---------- kernel 2: closed-form diagonal ----------
// dpart[i] = <a'_i, sum_k z_{ik}>  (t-units, a' prescaled)
__global__ __launch_bounds__(256) void diag_kernel(
    const unsigned short* __restrict__ a_bf,
    const unsigned short* __restrict__ z_bf, float* __restrict__ dpart) {
  int i    = blockIdx.x * 4 + (threadIdx.x >> 6);
  int lane = threadIdx.x & 63;
  ushort2 a2 = *(const ushort2*)(a_bf + i * DIM + lane * 2);
  float s0 = 0.f, s1 = 0.f;
  const unsigned short* zr = z_bf + (size_t)i * 16 * DIM + lane * 2;
  #pragma unroll
  for (int k = 0; k < 16; ++k) {
    ushort2 z2 = *(const ushort2*)(zr + k * DIM);
    s0 += bf2f(z2.x);
    s1 += bf2f(z2.y);
  }
  float d = bf2f(a2.x) * s0 + bf2f(a2.y) * s1;
  #pragma unroll
  for (int o = 32; o >= 1; o >>= 1) d += __shfl_xor(d, o);
  if (lane == 0) dpart[i] = d;
}

// ---------- kernel 3: fused GEMM + loss, DEPTH-3 prefetch pipeline ----------
// R8 post-mortem: per-phase cost ~3100cyc == exposed global-load latency at
// prefetch depth 1 (phase = max(work, latency)). Fix: 4 LDS buffers, stage
// tile t+3 each phase, vmcnt(6) steady (3 tiles / 6 loads in flight) ->
// phase = max(work, latency/3). XCD-swizzled blockIdx: 1MB B-slice per XCD.
__global__ __launch_bounds__(256) void gemm_loss_kernel(
    const unsigned short* __restrict__ a_bf,
    const unsigned short* __restrict__ z_bf,
    float* __restrict__ partial) {
  __shared__ __align__(16) unsigned short Bs[4][512 * 8];   // 4 x 8 KB
  __shared__ float red[4];

  const int t    = threadIdx.x;
  const int bid  = blockIdx.x;
  // bijective XCD swizzle (1024 % 8 == 0): XCD x -> cgi in [16x, 16x+16)
  const int lg   = ((bid & 7) << 7) | (bid >> 3);
  const int rb   = lg & 7;
  const int cgi  = lg >> 3;
  const int wave = t >> 6;
  const int lane = t & 63;
  const int c0   = cgi * CPB;

  // B stage source (fragment order for 32x32x16, verified R7): LDS slot
  // s = it*256 + t holds z[c0 + tile*32 + (s&31)][(s>>6)*16 + ((s>>5)&1)*8 ..+8]
  const unsigned short* pB;
  {
    int ks = t >> 6, col = t & 31, khalf = (t >> 5) & 1;
    pB = z_bf + (size_t)(c0 + col) * DIM + ks * 16 + khalf * 8;
  }

#define STAGE_B(buf, tt)                                                   \
  {                                                                        \
    const unsigned short* bg = pB + (size_t)(tt) * 32 * DIM;               \
    gload_lds16(bg, (buf) + (wave * 64) * 8);                              \
    gload_lds16(bg + 64, (buf) + (256 + wave * 64) * 8);                   \
  }

  STAGE_B(Bs[0], 0)

  // A fragments: af[i2][ks] = a[rb*256 + wave*64 + i2*32 + (lane&31)]
  //                             [ks*16 + (lane>>5)*8 .. +8]
  bf16x8 af[2][8];
  {
    const unsigned short* Ar =
        a_bf + (size_t)(rb * BM + wave * 64 + (lane & 31)) * DIM +
        (lane >> 5) * 8;
    #pragma unroll
    for (int i = 0; i < 2; ++i)
      #pragma unroll
      for (int ks = 0; ks < 8; ++ks)
        af[i][ks] = *(const bf16x8*)(Ar + i * 32 * DIM + ks * 16);
  }

  STAGE_B(Bs[1], 1)
  STAGE_B(Bs[2], 2)

  float sumt = 0.f, sumab = 0.f, logacc = 0.f;

  #pragma unroll 1
  for (int tt = 0; tt < NT; ++tt) {
    // stage tile tt+3; wait so tile tt's loads are done, 3 newer tiles
    // (6 loads) stay in flight. Exact tail counts.
    if (tt + 3 < NT) {
      STAGE_B(Bs[(tt + 3) & 3], tt + 3)
      asm volatile("s_waitcnt vmcnt(6)" ::: "memory");
    } else if (tt + 3 == NT) {
      asm volatile("s_waitcnt vmcnt(4)" ::: "memory");
    } else if (tt + 2 == NT) {
      asm volatile("s_waitcnt vmcnt(2)" ::: "memory");
    } else {
      asm volatile("s_waitcnt vmcnt(0)" ::: "memory");
    }
    __builtin_amdgcn_s_barrier();
    asm volatile("" ::: "memory");

    const unsigned short* Bb = Bs[tt & 3];

    f32x16 acc0, acc1;
    acc0 = 0.0f; acc1 = 0.0f;
    #pragma unroll
    for (int ks = 0; ks < 8; ++ks) {
      bf16x8 b = *(const bf16x8*)(Bb + (ks * 64 + lane) * 8);
      acc0 = __builtin_amdgcn_mfma_f32_32x32x16_bf16(af[0][ks], b, acc0, 0, 0, 0);
      acc1 = __builtin_amdgcn_mfma_f32_32x32x16_bf16(af[1][ks], b, acc1, 0, 0, 0);
    }

    // epilogue: add + |.|-add + exp2 + fma per element; 4 indep chains
    float st[4]  = {0.f, 0.f, 0.f, 0.f};
    float sab[4] = {0.f, 0.f, 0.f, 0.f};
    float pr[4]  = {1.f, 1.f, 1.f, 1.f};
    #pragma unroll
    for (int e = 0; e < 16; ++e) {
      float tv = acc0[e];
      int r = e & 3;
      st[r]  += tv;
      sab[r] += fabsf(tv);
      pr[r] = fmaf(pr[r], __builtin_amdgcn_exp2f(-fabsf(tv)), pr[r]);
    }
    #pragma unroll
    for (int e = 0; e < 16; ++e) {
      float tv = acc1[e];
      int r = e & 3;
      st[r]  += tv;
      sab[r] += fabsf(tv);
      pr[r] = fmaf(pr[r], __builtin_amdgcn_exp2f(-fabsf(tv)), pr[r]);
    }
    sumt  += (st[0] + st[1]) + (st[2] + st[3]);
    sumab += (sab[0] + sab[1]) + (sab[2] + sab[3]);
    // 8 factors in [1,2] per chain -> product <= 2^32: safe
    logacc += __builtin_amdgcn_logf((pr[0] * pr[1]) * (pr[2] * pr[3]));

    asm volatile("s_waitcnt lgkmcnt(0)" ::: "memory");
    __builtin_amdgcn_s_barrier();
    asm volatile("" ::: "memory");
  }

  float local = 0.5f * (sumt + sumab) + logacc;
  #pragma unroll
  for (int o = 32; o >= 1; o >>= 1) local += __shfl_xor(local, o);
  if (lane == 0) red[wave] = local;
  __syncthreads();
  if (t == 0) partial[bid] = (red[0] + red[1]) + (red[2] + red[3]);
}

// ---------- kernel 4: final reduction ----------
// out = LN2/N * (sum(partial) - sum(dpart))
__global__ __launch_bounds__(256) void reduce_kernel(
    const float* __restrict__ partial, const float* __restrict__ dpart,
    float* __restrict__ out) {
  int t = threadIdx.x;
  float s = 0.0f;
  for (int i = t; i < NBLK; i += 256) s += partial[i];
  for (int i = t; i < N_ANCHOR; i += 256) s -= dpart[i];
  #pragma unroll
  for (int o = 32; o >= 1; o >>= 1) s += __shfl_xor(s, o);
  __shared__ float red[4];
  if ((t & 63) == 0) red[t >> 6] = s;
  __syncthreads();
  if (t == 0)
    out[0] = ((red[0] + red[1]) + (red[2] + red[3])) * (LN2 / TOTAL_ELEMS);
}

extern "C" void kernel_launch(void* const* d_in, const int* in_sizes, int n_in,
                              void* d_out, int out_size, void* d_ws, size_t ws_size,
                              hipStream_t stream) {
  const float* anchor = (const float*)d_in[0];
  const float* pos    = (const float*)d_in[1];
  const float* neg    = (const float*)d_in[2];
  char* ws = (char*)d_ws;
  unsigned short* a_bf = (unsigned short*)ws;                    // 512 KB
  unsigned short* z_bf = (unsigned short*)(ws + 524288);         // 8 MB
  float* partial       = (float*)(ws + 524288 + 8388608);        // 4 KB
  float* dpart         = (float*)(ws + 524288 + 8388608 + 4096); // 8 KB

  norm_kernel<<<dim3(NROWS / 8), dim3(256), 0, stream>>>(
      anchor, pos, neg, a_bf, z_bf);
  diag_kernel<<<dim3(N_ANCHOR / 4), dim3(256), 0, stream>>>(a_bf, z_bf, dpart);
  gemm_loss_kernel<<<dim3(NBLK), dim3(256), 0, stream>>>(a_bf, z_bf, partial);
  reduce_kernel<<<dim3(1), dim3(256), 0, stream>>>(partial, dpart,
                                                   (float*)d_out);
}